// Round 6
// baseline (113.631 us; speedup 1.0000x reference)
//
#include <hip/hip_runtime.h>

// 8-connected CCL on a 2048x2048 mask (prob > 0.5).
// Output int32: (component min flat index)+1 for fg, 0 for bg.
//
//   1. k_local   : per 128x128 tile (64KB LDS), ballot/run-based union-find.
//                  Rows are 2 wave64 ballots; labels init to the ROW-GLOBAL
//                  run-start index (no horizontal unions at all); vertical
//                  unions fire once per run-overlap segment. Run starts are
//                  CACHED IN REGISTERS (slab roots mutate under concurrent
//                  unions -- re-reading them for control decisions races).
//   2. k_border  : cross-tile unions, ONE union per thread, implied-link
//                  dedup, path-halving finds. Parent reads use agent-scope
//                  atomic loads (bypass stale non-coherent L1).
//   3. k_compress: chase to true root; 1-based encoding (0=bg) makes the
//                  compressed value the final output directly.

#define H 2048
#define W 2048
#define NPIX (H * W)
#define TS 128            // tile side
#define ROWS_PER_THREAD 8 // 128 rows / 16 ty

__device__ __forceinline__ int aload(const int* p) {
    // coherent (agent-scope) load: bypasses per-CU L1, reads L2 truth.
    return __hip_atomic_load(p, __ATOMIC_RELAXED, __HIP_MEMORY_SCOPE_AGENT);
}

// ---------- global union-find, 1-based parents, with path halving ----------
__device__ __forceinline__ int gfind(int* __restrict__ L, int a) {
    int n = aload(&L[a]);
    while (n != a + 1) {
        int p = n - 1;
        int g = aload(&L[p]);             // grandparent+1
        // Path halving MUST be atomicMin: plain store could overwrite a
        // concurrent union's smaller parent. g is same-component & smaller.
        if (g != n) atomicMin(&L[a], g);
        a = p; n = g;
    }
    return a;
}

__device__ __forceinline__ void gunite(int* __restrict__ L, int a, int b) {
    while (true) {
        a = gfind(L, a);
        b = gfind(L, b);
        if (a == b) return;
        if (a > b) { int t = a; a = b; b = t; }
        int old = atomicMin(&L[b], a + 1);
        if (old == b + 1) return;
        b = old - 1;
    }
}

// ---------- local (LDS) union-find, 0-based, -1 = background ----------
__device__ __forceinline__ int lfind(volatile int* L, int a) {
    int n = L[a];
    while (n != a) { a = n; n = L[a]; }
    return a;
}

__device__ __forceinline__ void lunite(int* L, int a, int b) {
    volatile int* Lv = L;
    while (true) {
        a = lfind(Lv, a);
        b = lfind(Lv, b);
        if (a == b) return;
        if (a > b) { int t = a; a = b; b = t; }
        int old = atomicMin(&L[b], a);
        if (old == b) return;
        b = old;
    }
}

// run start (smallest s<=p with bits s..p all set; requires bit p set)
__device__ __forceinline__ int run_start64(unsigned long long m, int p) {
    if (p == 0) return 0;
    unsigned long long below = m << (64 - p);   // bit p-1 -> bit 63
    return p - __builtin_clzll(~below);         // minus count of leading ones
}

// row-global run start over a 128-bit row mask (u0 = cols 0..63, u1 = 64..127)
__device__ __forceinline__ int run_start128(unsigned long long u0,
                                            unsigned long long u1, int p) {
    if (p >= 64) {
        int s = run_start64(u1, p - 64) + 64;
        if (s == 64 && (u0 >> 63)) s = run_start64(u0, 63);  // continues left
        return s;
    }
    return run_start64(u0, p);
}

__device__ __forceinline__ int getbit128(unsigned long long u0,
                                         unsigned long long u1, int p) {
    if (p < 0 || p > 127) return 0;
    return (int)((p < 64 ? (u0 >> p) : (u1 >> (p - 64))) & 1ull);
}

__global__ __launch_bounds__(1024)
void k_local(const float* __restrict__ prob, int* __restrict__ lab) {
    __shared__ int slab[TS * TS];               // 65536 B exactly
    const int x0 = blockIdx.x * TS, y0 = blockIdx.y * TS;
    const int lx = threadIdx.x;                 // 0..63 == lane
    const int ty = threadIdx.y;                 // 0..15

    unsigned long long rM0[ROWS_PER_THREAD], rM1[ROWS_PER_THREAD];
    int sA[ROWS_PER_THREAD], sB[ROWS_PER_THREAD];  // run starts, reg-cached

    // init: two ballots per row; label := row-global run start (kills all
    // horizontal unions, including across the 64-lane segment boundary)
    #pragma unroll
    for (int k = 0; k < ROWS_PER_THREAD; ++k) {
        int ly = ty * ROWS_PER_THREAD + k;
        const float* rowp = prob + (long)(y0 + ly) * W + x0;
        bool f0 = rowp[lx] > 0.5f;
        bool f1 = rowp[64 + lx] > 0.5f;
        unsigned long long m0 = __ballot(f0);
        unsigned long long m1 = __ballot(f1);
        rM0[k] = m0; rM1[k] = m1;
        int s0 = f0 ? run_start128(m0, m1, lx) : lx;
        int s1 = f1 ? run_start128(m0, m1, 64 + lx) : 64 + lx;
        sA[k] = s0; sB[k] = s1;
        slab[ly * TS + lx]      = f0 ? ly * TS + s0 : -1;
        slab[ly * TS + 64 + lx] = f1 ? ly * TS + s1 : -1;
    }
    __syncthreads();

    // vertical unions, once per (my-run, upper-segment) overlap:
    //   N  at leftmost covered position of each contiguous upper segment
    //   NW only at run start (upper-left set, upper clear)
    //   NE only at run end   (upper-right set, upper clear)
    // Control decisions use ONLY register-cached masks/run-starts; slab root
    // entries mutate under concurrent lunite calls.
    #pragma unroll
    for (int k = 0; k < ROWS_PER_THREAD; ++k) {
        int ly = ty * ROWS_PER_THREAD + k;
        if (ly == 0) continue;
        // upper row mask via ballot over slab (bg(-1)/fg(>=0) sign is stable)
        unsigned long long u0 = __ballot(slab[(ly - 1) * TS + lx] >= 0);
        unsigned long long u1 = __ballot(slab[(ly - 1) * TS + 64 + lx] >= 0);
        unsigned long long m0 = rM0[k], m1 = rM1[k];
        #pragma unroll
        for (int h = 0; h < 2; ++h) {
            int pos = h * 64 + lx;
            if (!getbit128(m0, m1, pos)) continue;
            int s = h ? sB[k] : sA[k];               // my run start (registers)
            int mylab = ly * TS + s;
            if (getbit128(u0, u1, pos)) {
                if (pos == s || !getbit128(u0, u1, pos - 1))
                    lunite(slab, mylab, (ly - 1) * TS + run_start128(u0, u1, pos));
            } else {
                if (pos == s && getbit128(u0, u1, pos - 1))
                    lunite(slab, mylab, (ly - 1) * TS + run_start128(u0, u1, pos - 1));
                bool isEnd = (pos == 127) || !getbit128(m0, m1, pos + 1);
                if (isEnd && getbit128(u0, u1, pos + 1))
                    lunite(slab, mylab, (ly - 1) * TS + (pos + 1)); // u[pos]=0 -> run starts there
            }
        }
    }
    __syncthreads();

    // flatten: parent := global index of tile root (= min local index)
    #pragma unroll
    for (int k = 0; k < ROWS_PER_THREAD; ++k) {
        int ly = ty * ROWS_PER_THREAD + k;
        #pragma unroll
        for (int h = 0; h < 2; ++h) {
            int li = ly * TS + h * 64 + lx;
            int out = 0;
            if (slab[li] >= 0) {
                int r = lfind(slab, li);
                out = (y0 + (r >> 7)) * W + (x0 + (r & 127)) + 1;
            }
            lab[(long)(y0 + ly) * W + x0 + h * 64 + lx] = out;
        }
    }
}

// Cross-tile unions: 6 segments x 32768 threads, ONE union max per thread.
//   seg 0: lx==0   W   (skip if ly>0 && N fg && NW fg -- vertical-run dedup,
//                       grounds at ly==0 where W is always issued)
//   seg 1: lx==0   NW  (ly>0; skip if N fg: me~N intra + N~NW via seg0)
//   seg 2: lx==127 NE  (ly>0; skip if N fg: me~N intra + N~NE via seg0)
//   seg 3: ly==0   NW  (skip if west fg -- run-start dedup)
//   seg 4: ly==0   N   (skip if west fg)
//   seg 5: ly==0   NE  (never skipped -- anchors the horizontal dedup proof)
__global__ __launch_bounds__(256)
void k_border(int* __restrict__ lab) {
    int tid = blockIdx.x * blockDim.x + threadIdx.x;
    int seg = tid >> 15;
    int r = tid & 32767;

    if (seg < 3) {                       // vertical seams (16 tile columns)
        int y = r >> 4;
        int ly = y & (TS - 1);
        if (seg == 0) {
            int x = (r & 15) << 7;
            if (x == 0) return;
            int i = y * W + x;
            int vi = lab[i];           if (!vi) return;
            int vw = lab[i - 1];       if (!vw) return;
            if (ly > 0 && lab[i - W] && lab[i - W - 1]) return;
            gunite(lab, vi - 1, vw - 1);
        } else if (seg == 1) {
            int x = (r & 15) << 7;
            if (x == 0 || ly == 0 || y == 0) return;
            int i = y * W + x;
            int vi = lab[i];           if (!vi) return;
            int vn = lab[i - W - 1];   if (!vn) return;
            if (lab[i - W]) return;
            gunite(lab, vi - 1, vn - 1);
        } else {
            int x = ((r & 15) << 7) + (TS - 1);
            if (x >= W - 1 || ly == 0 || y == 0) return;
            int i = y * W + x;
            int vi = lab[i];           if (!vi) return;
            int vn = lab[i - W + 1];   if (!vn) return;
            if (lab[i - W]) return;
            gunite(lab, vi - 1, vn - 1);
        }
    } else {                             // horizontal seam rows (ly == 0)
        int x = r & (W - 1);
        int y = (r >> 11) << 7;
        if (y == 0) return;
        int i = y * W + x;
        int vi = lab[i];               if (!vi) return;
        if (seg == 3) {
            if (x == 0) return;
            int vn = lab[i - W - 1];   if (!vn) return;
            if (lab[i - 1]) return;
            gunite(lab, vi - 1, vn - 1);
        } else if (seg == 4) {
            int vn = lab[i - W];       if (!vn) return;
            if (x > 0 && lab[i - 1]) return;
            gunite(lab, vi - 1, vn - 1);
        } else {
            if (x == W - 1) return;
            int vn = lab[i - W + 1];   if (!vn) return;
            gunite(lab, vi - 1, vn - 1);
        }
    }
}

__global__ __launch_bounds__(256)
void k_compress(int* __restrict__ lab) {
    int i = blockIdx.x * blockDim.x + threadIdx.x;
    if (i >= NPIX) return;
    int v = lab[i];
    if (v == 0 || v == i + 1) return;
    int r = gfind(lab, v - 1);
    lab[i] = r + 1;                      // root+1 is the global min -> plain store ok
}

extern "C" void kernel_launch(void* const* d_in, const int* in_sizes, int n_in,
                              void* d_out, int out_size, void* d_ws, size_t ws_size,
                              hipStream_t stream) {
    const float* prob = (const float*)d_in[0];
    int* lab = (int*)d_out;

    dim3 lgrid(W / TS, H / TS);          // 16 x 16
    dim3 lblock(64, 16);                 // 1024 threads, 16 waves
    k_local<<<lgrid, lblock, 0, stream>>>(prob, lab);

    const int nborder = 6 * 32768;
    k_border<<<nborder / 256, 256, 0, stream>>>(lab);

    k_compress<<<NPIX / 256, 256, 0, stream>>>(lab);
}

// Round 7
// 107.513 us; speedup vs baseline: 1.0569x; 1.0569x over previous
//
#include <hip/hip_runtime.h>

// 8-connected CCL on a 2048x2048 mask (prob > 0.5).
// Output int32: (component min flat index)+1 for fg, 0 for bg.
//
//   1. k_local   : per 128x128 tile (64KB LDS), ballot/run-based union-find.
//                  Labels init to ROW-GLOBAL run-start (no horizontal unions);
//                  vertical unions once per run-overlap segment; flatten via
//                  run-start pre-flatten + one LDS read per pixel.
//   2. k_seam    : cross-tile unions. One wave per 128-px seam chunk; both
//                  sides' masks via ballot; EXACTLY ONE gunite per
//                  (run, run) overlap segment (leftmost-covered / left-touch /
//                  right-touch rules). 4-corner diagonals handled by the
//                  horizontal chunks' edge lanes.
//   3. k_compress: chase to true root; 1-based encoding (0=bg) makes the
//                  compressed value the final output directly.

#define H 2048
#define W 2048
#define NPIX (H * W)
#define TS 128            // tile side
#define RPT 8             // rows per thread in k_local

__device__ __forceinline__ int aload(const int* p) {
    // coherent (agent-scope) load: bypasses per-CU L1, reads L2 truth.
    return __hip_atomic_load(p, __ATOMIC_RELAXED, __HIP_MEMORY_SCOPE_AGENT);
}

// ---------- global union-find, 1-based parents, with path halving ----------
__device__ __forceinline__ int gfind(int* __restrict__ L, int a) {
    int n = aload(&L[a]);
    while (n != a + 1) {
        int p = n - 1;
        int g = aload(&L[p]);             // grandparent+1
        // Path halving MUST be atomicMin: plain store could overwrite a
        // concurrent union's smaller parent. g is same-component & smaller.
        if (g != n) atomicMin(&L[a], g);
        a = p; n = g;
    }
    return a;
}

__device__ __forceinline__ void gunite(int* __restrict__ L, int a, int b) {
    while (true) {
        a = gfind(L, a);
        b = gfind(L, b);
        if (a == b) return;
        if (a > b) { int t = a; a = b; b = t; }
        int old = atomicMin(&L[b], a + 1);
        if (old == b + 1) return;
        b = old - 1;
    }
}

// ---------- local (LDS) union-find, 0-based, -1 = background ----------
__device__ __forceinline__ int lfind(volatile int* L, int a) {
    int n = L[a];
    while (n != a) { a = n; n = L[a]; }
    return a;
}

__device__ __forceinline__ void lunite(int* L, int a, int b) {
    volatile int* Lv = L;
    while (true) {
        a = lfind(Lv, a);
        b = lfind(Lv, b);
        if (a == b) return;
        if (a > b) { int t = a; a = b; b = t; }
        int old = atomicMin(&L[b], a);
        if (old == b) return;
        b = old;
    }
}

// run start (smallest s<=p with bits s..p all set; requires bit p set)
__device__ __forceinline__ int run_start64(unsigned long long m, int p) {
    if (p == 0) return 0;
    unsigned long long below = m << (64 - p);   // bit p-1 -> bit 63
    return p - __builtin_clzll(~below);         // minus count of leading ones
}

// run start over a 128-bit mask (u0 = positions 0..63, u1 = 64..127)
__device__ __forceinline__ int run_start128(unsigned long long u0,
                                            unsigned long long u1, int p) {
    if (p >= 64) {
        int s = run_start64(u1, p - 64) + 64;
        if (s == 64 && (u0 >> 63)) s = run_start64(u0, 63);  // continues left
        return s;
    }
    return run_start64(u0, p);
}

__device__ __forceinline__ int getbit128(unsigned long long u0,
                                         unsigned long long u1, int p) {
    if (p < 0 || p > 127) return 0;
    return (int)((p < 64 ? (u0 >> p) : (u1 >> (p - 64))) & 1ull);
}

__global__ __launch_bounds__(1024)
void k_local(const float* __restrict__ prob, int* __restrict__ lab) {
    __shared__ int slab[TS * TS];               // 65536 B exactly
    const int x0 = blockIdx.x * TS, y0 = blockIdx.y * TS;
    const int lx = threadIdx.x;                 // 0..63 == lane
    const int ty = threadIdx.y;                 // 0..15

    unsigned long long rM0[RPT], rM1[RPT];
    int sA[RPT], sB[RPT];                       // run starts, register-cached

    // init: two ballots per row; label := row-global run start
    #pragma unroll
    for (int k = 0; k < RPT; ++k) {
        int ly = ty * RPT + k;
        const float* rowp = prob + (long)(y0 + ly) * W + x0;
        bool f0 = rowp[lx] > 0.5f;
        bool f1 = rowp[64 + lx] > 0.5f;
        unsigned long long m0 = __ballot(f0);
        unsigned long long m1 = __ballot(f1);
        rM0[k] = m0; rM1[k] = m1;
        int s0 = f0 ? run_start128(m0, m1, lx) : lx;
        int s1 = f1 ? run_start128(m0, m1, 64 + lx) : 64 + lx;
        sA[k] = s0; sB[k] = s1;
        slab[ly * TS + lx]      = f0 ? ly * TS + s0 : -1;
        slab[ly * TS + 64 + lx] = f1 ? ly * TS + s1 : -1;
    }
    __syncthreads();

    // vertical unions, once per (my-run, upper-segment) overlap.
    // Control uses ONLY register-cached masks/run-starts (slab roots mutate).
    #pragma unroll
    for (int k = 0; k < RPT; ++k) {
        int ly = ty * RPT + k;
        if (ly == 0) continue;
        unsigned long long u0 = __ballot(slab[(ly - 1) * TS + lx] >= 0);
        unsigned long long u1 = __ballot(slab[(ly - 1) * TS + 64 + lx] >= 0);
        unsigned long long m0 = rM0[k], m1 = rM1[k];
        #pragma unroll
        for (int h = 0; h < 2; ++h) {
            int pos = h * 64 + lx;
            if (!getbit128(m0, m1, pos)) continue;
            int s = h ? sB[k] : sA[k];
            int mylab = ly * TS + s;
            if (getbit128(u0, u1, pos)) {
                if (pos == s || !getbit128(u0, u1, pos - 1))
                    lunite(slab, mylab, (ly - 1) * TS + run_start128(u0, u1, pos));
            } else {
                if (pos == s && getbit128(u0, u1, pos - 1))
                    lunite(slab, mylab, (ly - 1) * TS + run_start128(u0, u1, pos - 1));
                bool isEnd = (pos == 127) || !getbit128(m0, m1, pos + 1);
                if (isEnd && getbit128(u0, u1, pos + 1))
                    lunite(slab, mylab, (ly - 1) * TS + (pos + 1));
            }
        }
    }
    __syncthreads();

    // flatten step a: pre-flatten RUN-START entries only (~4K lfinds).
    // Tree is static now; plain stores write true roots (root entries
    // self-point, so concurrent readers just shortcut).
    #pragma unroll
    for (int k = 0; k < RPT; ++k) {
        int ly = ty * RPT + k;
        unsigned long long m0 = rM0[k], m1 = rM1[k];
        if (((m0 >> lx) & 1) && sA[k] == lx) {
            int li = ly * TS + lx;
            slab[li] = lfind(slab, li);
        }
        if (((m1 >> lx) & 1) && sB[k] == 64 + lx) {
            int li = ly * TS + 64 + lx;
            slab[li] = lfind(slab, li);
        }
    }
    __syncthreads();

    // flatten step b: one LDS read at the register-cached run start
    // (same-run lanes hit the same bank word -> broadcast, conflict-free).
    #pragma unroll
    for (int k = 0; k < RPT; ++k) {
        int ly = ty * RPT + k;
        unsigned long long m0 = rM0[k], m1 = rM1[k];
        int out0 = 0, out1 = 0;
        if ((m0 >> lx) & 1) {
            int r = slab[ly * TS + sA[k]];
            out0 = (y0 + (r >> 7)) * W + (x0 + (r & 127)) + 1;
        }
        if ((m1 >> lx) & 1) {
            int r = slab[ly * TS + sB[k]];
            out1 = (y0 + (r >> 7)) * W + (x0 + (r & 127)) + 1;
        }
        lab[(long)(y0 + ly) * W + x0 + lx]      = out0;
        lab[(long)(y0 + ly) * W + x0 + 64 + lx] = out1;
    }
}

// Cross-tile seam merge. 480 wave-tasks (240 vertical + 240 horizontal);
// each wave owns one 128-px chunk of one seam (chunk == one tile edge, so
// every mask-run on either side has a UNIFORM lab value -> run dedup valid).
// Per (B-run, A-run) overlap segment exactly one gunite:
//   covered   : leftmost pos of the A-segment inside my run
//   left-touch: my run start, A set only at pos-1 (in-chunk)
//   right-touch: my run end,  A set only at pos+1 (in-chunk)
// Out-of-chunk contacts (4-tile corners) are handled ONLY by the horizontal
// chunks' edge lanes: NW corner (b[0] fg, a[0] bg, a[-1] fg) and NE corner
// (b[127] fg, a[127] bg, a[128] fg). The vertical analogs of those corner
// links are exactly the same pixel pairs, so vertical chunks skip them.
__global__ __launch_bounds__(256)
void k_seam(int* __restrict__ lab) {
    int gtid = blockIdx.x * blockDim.x + threadIdx.x;
    int task = gtid >> 6;
    int lane = gtid & 63;
    bool vertical = task < 240;
    int t = vertical ? task : task - 240;
    int seam = t >> 4;       // 0..14
    int chunk = t & 15;

    long baseB, baseA, step;
    int B0, B1, A0, A1;
    if (vertical) {
        int x = (seam + 1) << 7;           // seam column (tile-left edge)
        int ybase = chunk << 7;
        baseB = (long)ybase * W + x;
        baseA = baseB - 1;
        step = W;
        B0 = lab[baseB + (long)lane * W];
        B1 = lab[baseB + (long)(lane + 64) * W];
        A0 = lab[baseA + (long)lane * W];
        A1 = lab[baseA + (long)(lane + 64) * W];
    } else {
        int y = (seam + 1) << 7;           // seam row (tile-top edge)
        int xbase = chunk << 7;
        baseB = (long)y * W + xbase;
        baseA = baseB - W;
        step = 1;
        B0 = lab[baseB + lane];
        B1 = lab[baseB + 64 + lane];
        A0 = lab[baseA + lane];
        A1 = lab[baseA + 64 + lane];
    }
    unsigned long long m0 = __ballot(B0 != 0), m1 = __ballot(B1 != 0);
    unsigned long long u0 = __ballot(A0 != 0), u1 = __ballot(A1 != 0);

    #pragma unroll
    for (int h = 0; h < 2; ++h) {
        int pos = (h << 6) | lane;
        if (!getbit128(m0, m1, pos)) continue;
        int myB = h ? B1 : B0;
        int s = run_start128(m0, m1, pos);
        if (getbit128(u0, u1, pos)) {
            if (pos == s || !getbit128(u0, u1, pos - 1)) {
                int tgt = h ? A1 : A0;              // contact pixel's label
                gunite(lab, myB - 1, tgt - 1);
            }
        } else {
            if (pos == s && pos > 0 && getbit128(u0, u1, pos - 1)) {
                int tgt = lab[baseA + (long)(pos - 1) * step];
                gunite(lab, myB - 1, tgt - 1);
            }
            bool isEnd = (pos == 127) || !getbit128(m0, m1, pos + 1);
            if (isEnd && pos < 127 && getbit128(u0, u1, pos + 1)) {
                int tgt = lab[baseA + (long)(pos + 1) * step];
                gunite(lab, myB - 1, tgt - 1);
            }
        }
    }

    // 4-tile-corner diagonal links (horizontal chunks only, edge lanes)
    if (!vertical && lane == 0) {
        int y = (seam + 1) << 7;
        int xbase = chunk << 7;
        if (xbase > 0 && (m0 & 1) && !(u0 & 1)) {          // NW corner
            int tgt = lab[(long)(y - 1) * W + xbase - 1];
            if (tgt) gunite(lab, B0 - 1, tgt - 1);
        }
        if (xbase + 128 < W && ((m1 >> 63) & 1) && !((u1 >> 63) & 1)) {  // NE
            int tgt = lab[(long)(y - 1) * W + xbase + 128];
            if (tgt) {
                int b127 = lab[(long)y * W + xbase + 127];
                gunite(lab, b127 - 1, tgt - 1);
            }
        }
    }
}

__global__ __launch_bounds__(256)
void k_compress(int* __restrict__ lab) {
    int i = blockIdx.x * blockDim.x + threadIdx.x;
    if (i >= NPIX) return;
    int v = lab[i];
    if (v == 0 || v == i + 1) return;    // bg or already root
    // Roots are FIXED during this kernel (no unions), so stale-L1 plain
    // loads inside gfind still terminate at a true root; halving atomicMins
    // only shorten chains.
    int r = gfind(lab, v - 1);
    if (r + 1 != v) lab[i] = r + 1;      // root+1 is the component min
}

extern "C" void kernel_launch(void* const* d_in, const int* in_sizes, int n_in,
                              void* d_out, int out_size, void* d_ws, size_t ws_size,
                              hipStream_t stream) {
    const float* prob = (const float*)d_in[0];
    int* lab = (int*)d_out;

    dim3 lgrid(W / TS, H / TS);          // 16 x 16
    dim3 lblock(64, 16);                 // 1024 threads, 16 waves
    k_local<<<lgrid, lblock, 0, stream>>>(prob, lab);

    // 480 wave-tasks * 64 lanes = 30720 threads = 120 blocks exactly
    k_seam<<<120, 256, 0, stream>>>(lab);

    k_compress<<<NPIX / 256, 256, 0, stream>>>(lab);
}

// Round 8
// 93.257 us; speedup vs baseline: 1.2185x; 1.1529x over previous
//
#include <hip/hip_runtime.h>

// 8-connected CCL on a 2048x2048 mask (prob > 0.5).
// Output int32: (component min flat index)+1 for fg, 0 for bg.
//
//   1. k_local   : per 128x64 tile (32KB LDS, 2 blocks/CU), ballot/run-based
//                  union-find. Labels init to ROW-GLOBAL run-start (no
//                  horizontal unions); vertical unions once per run-overlap
//                  segment; flatten via run-start pre-flatten + one LDS read.
//   2. k_seam    : cross-tile unions. One wave per 128-px seam chunk; ONE
//                  gunite per (run,run) overlap segment. Chunks may cross
//                  perpendicular tile boundaries: correct by transitivity,
//                  because intra-run cross-boundary links are supplied by the
//                  perpendicular seam's own overlap unions. 4-corner
//                  diagonals (x=128c, y=64k) handled by horizontal chunks'
//                  edge lanes.
//   3. k_compress: READ-ONLY chase to root (tree is static here -- halving
//                  atomicMins would just serialize on hot root lines).

#define H 2048
#define W 2048
#define NPIX (H * W)
#define TSX 128           // tile width  (mask = 2 x u64)
#define TSY 64            // tile height
#define RPT 4             // rows per thread = TSY / 16

__device__ __forceinline__ int aload(const int* p) {
    // coherent (agent-scope) load: bypasses per-CU L1, reads L2 truth.
    return __hip_atomic_load(p, __ATOMIC_RELAXED, __HIP_MEMORY_SCOPE_AGENT);
}

// ---------- global union-find, 1-based parents (0 = background) ----------
__device__ __forceinline__ int gfind(int* __restrict__ L, int a) {
    int n = aload(&L[a]);
    while (n != a + 1) {
        int p = n - 1;
        int g = aload(&L[p]);             // grandparent+1
        // halving MUST be atomicMin: plain store could overwrite a
        // concurrent union's smaller parent. g is same-component & smaller.
        if (g != n) atomicMin(&L[a], g);
        a = p; n = g;
    }
    return a;
}

__device__ __forceinline__ void gunite(int* __restrict__ L, int a, int b) {
    while (true) {
        a = gfind(L, a);
        b = gfind(L, b);
        if (a == b) return;
        if (a > b) { int t = a; a = b; b = t; }
        int old = atomicMin(&L[b], a + 1);
        if (old == b + 1) return;
        b = old - 1;
    }
}

// ---------- local (LDS) union-find, 0-based, -1 = background ----------
__device__ __forceinline__ int lfind(volatile int* L, int a) {
    int n = L[a];
    while (n != a) { a = n; n = L[a]; }
    return a;
}

// find with atomicMin path-halving (safe under concurrent unions: parents
// only decrease and remain in-component)
__device__ __forceinline__ int lfind_h(int* L, int a) {
    volatile int* Lv = L;
    int n = Lv[a];
    while (n != a) {
        int g = Lv[n];
        if (g != n) atomicMin(&L[a], g);
        a = n; n = g;
    }
    return a;
}

__device__ __forceinline__ void lunite(int* L, int a, int b) {
    while (true) {
        a = lfind_h(L, a);
        b = lfind_h(L, b);
        if (a == b) return;
        if (a > b) { int t = a; a = b; b = t; }
        int old = atomicMin(&L[b], a);
        if (old == b) return;
        b = old;
    }
}

// run start (smallest s<=p with bits s..p all set; requires bit p set)
__device__ __forceinline__ int run_start64(unsigned long long m, int p) {
    if (p == 0) return 0;
    unsigned long long below = m << (64 - p);   // bit p-1 -> bit 63
    return p - __builtin_clzll(~below);         // minus count of leading ones
}

__device__ __forceinline__ int run_start128(unsigned long long u0,
                                            unsigned long long u1, int p) {
    if (p >= 64) {
        int s = run_start64(u1, p - 64) + 64;
        if (s == 64 && (u0 >> 63)) s = run_start64(u0, 63);  // continues left
        return s;
    }
    return run_start64(u0, p);
}

__device__ __forceinline__ int getbit128(unsigned long long u0,
                                         unsigned long long u1, int p) {
    if (p < 0 || p > 127) return 0;
    return (int)((p < 64 ? (u0 >> p) : (u1 >> (p - 64))) & 1ull);
}

__global__ __launch_bounds__(1024)
void k_local(const float* __restrict__ prob, int* __restrict__ lab) {
    __shared__ int slab[TSY * TSX];                       // 32 KB
    __shared__ unsigned long long mrow0[TSY], mrow1[TSY]; // 1 KB mask table
    const int x0 = blockIdx.x * TSX, y0 = blockIdx.y * TSY;
    const int lx = threadIdx.x;                 // 0..63 == lane
    const int ty = threadIdx.y;                 // 0..15

    unsigned long long rM0[RPT], rM1[RPT];
    int sA[RPT], sB[RPT];                       // run starts, register-cached

    // init: two ballots per row; label := row-global run start (kills all
    // horizontal unions, incl. across the 64-lane segment boundary)
    #pragma unroll
    for (int k = 0; k < RPT; ++k) {
        int ly = ty * RPT + k;
        const float* rowp = prob + (long)(y0 + ly) * W + x0;
        bool f0 = rowp[lx] > 0.5f;
        bool f1 = rowp[64 + lx] > 0.5f;
        unsigned long long m0 = __ballot(f0);
        unsigned long long m1 = __ballot(f1);
        rM0[k] = m0; rM1[k] = m1;
        int s0 = f0 ? run_start128(m0, m1, lx) : lx;
        int s1 = f1 ? run_start128(m0, m1, 64 + lx) : 64 + lx;
        sA[k] = s0; sB[k] = s1;
        slab[ly * TSX + lx]      = f0 ? ly * TSX + s0 : -1;
        slab[ly * TSX + 64 + lx] = f1 ? ly * TSX + s1 : -1;
        if (lx == 0) { mrow0[ly] = m0; mrow1[ly] = m1; }
    }
    __syncthreads();

    // vertical unions, once per (my-run, upper-segment) overlap.
    // Control uses ONLY register-cached / mask-table values (slab roots
    // mutate under concurrent lunite -- round-4 lesson).
    #pragma unroll
    for (int k = 0; k < RPT; ++k) {
        int ly = ty * RPT + k;
        if (ly == 0) continue;
        unsigned long long u0 = mrow0[ly - 1], u1 = mrow1[ly - 1];
        unsigned long long m0 = rM0[k], m1 = rM1[k];
        #pragma unroll
        for (int h = 0; h < 2; ++h) {
            int pos = h * 64 + lx;
            if (!getbit128(m0, m1, pos)) continue;
            int s = h ? sB[k] : sA[k];
            int mylab = ly * TSX + s;
            if (getbit128(u0, u1, pos)) {
                if (pos == s || !getbit128(u0, u1, pos - 1))
                    lunite(slab, mylab, (ly - 1) * TSX + run_start128(u0, u1, pos));
            } else {
                if (pos == s && getbit128(u0, u1, pos - 1))
                    lunite(slab, mylab, (ly - 1) * TSX + run_start128(u0, u1, pos - 1));
                bool isEnd = (pos == 127) || !getbit128(m0, m1, pos + 1);
                if (isEnd && getbit128(u0, u1, pos + 1))
                    lunite(slab, mylab, (ly - 1) * TSX + (pos + 1));
            }
        }
    }
    __syncthreads();

    // flatten step a: pre-flatten RUN-START entries only. Tree is static
    // now; plain stores write true roots.
    #pragma unroll
    for (int k = 0; k < RPT; ++k) {
        int ly = ty * RPT + k;
        unsigned long long m0 = rM0[k], m1 = rM1[k];
        if (((m0 >> lx) & 1) && sA[k] == lx) {
            int li = ly * TSX + lx;
            slab[li] = lfind(slab, li);
        }
        if (((m1 >> lx) & 1) && sB[k] == 64 + lx) {
            int li = ly * TSX + 64 + lx;
            slab[li] = lfind(slab, li);
        }
    }
    __syncthreads();

    // flatten step b: one LDS read at the register-cached run start
    // (same-run lanes hit one bank word -> broadcast).
    #pragma unroll
    for (int k = 0; k < RPT; ++k) {
        int ly = ty * RPT + k;
        unsigned long long m0 = rM0[k], m1 = rM1[k];
        int out0 = 0, out1 = 0;
        if ((m0 >> lx) & 1) {
            int r = slab[ly * TSX + sA[k]];
            out0 = (y0 + (r >> 7)) * W + (x0 + (r & 127)) + 1;
        }
        if ((m1 >> lx) & 1) {
            int r = slab[ly * TSX + sB[k]];
            out1 = (y0 + (r >> 7)) * W + (x0 + (r & 127)) + 1;
        }
        lab[(long)(y0 + ly) * W + x0 + lx]      = out0;
        lab[(long)(y0 + ly) * W + x0 + 64 + lx] = out1;
    }
}

// Cross-tile seam merge. 736 wave-tasks: 240 vertical (15 seam columns at
// x=128c, 16 chunks of 128 rows) + 496 horizontal (31 seam rows at y=64k,
// 16 chunks of 128 cols). One gunite per (B-run, A-run) overlap segment:
//   covered    : leftmost pos of the A-segment inside my run
//   left-touch : my run start, A set only at pos-1 (in-chunk)
//   right-touch: my run end,  A set only at pos+1 (in-chunk)
// Chunks crossing perpendicular tile boundaries stay correct: a run with
// multiple tile labels is internally united by the perpendicular seam's own
// overlap unions (transitivity). Out-of-chunk corner contacts at
// (y=64k multiple-of-128-aligned or not, x=128c) are handled ONLY by the
// horizontal chunks' edge lanes below (possibly redundantly -- harmless).
__global__ __launch_bounds__(256)
void k_seam(int* __restrict__ lab) {
    int gtid = blockIdx.x * blockDim.x + threadIdx.x;
    int task = gtid >> 6;
    int lane = gtid & 63;
    bool vertical = task < 240;
    int t = vertical ? task : task - 240;
    int seam, chunk;

    long baseB, baseA, step;
    int B0, B1, A0, A1;
    if (vertical) {
        seam = t >> 4; chunk = t & 15;
        int x = (seam + 1) << 7;           // seam column
        int ybase = chunk << 7;            // 128-row chunk
        baseB = (long)ybase * W + x;
        baseA = baseB - 1;
        step = W;
        B0 = lab[baseB + (long)lane * W];
        B1 = lab[baseB + (long)(lane + 64) * W];
        A0 = lab[baseA + (long)lane * W];
        A1 = lab[baseA + (long)(lane + 64) * W];
    } else {
        seam = t >> 4; chunk = t & 15;     // seam 0..30
        int y = (seam + 1) << 6;           // seam row (every 64)
        int xbase = chunk << 7;
        baseB = (long)y * W + xbase;
        baseA = baseB - W;
        step = 1;
        B0 = lab[baseB + lane];
        B1 = lab[baseB + 64 + lane];
        A0 = lab[baseA + lane];
        A1 = lab[baseA + 64 + lane];
    }
    unsigned long long m0 = __ballot(B0 != 0), m1 = __ballot(B1 != 0);
    unsigned long long u0 = __ballot(A0 != 0), u1 = __ballot(A1 != 0);

    #pragma unroll
    for (int h = 0; h < 2; ++h) {
        int pos = (h << 6) | lane;
        if (!getbit128(m0, m1, pos)) continue;
        int myB = h ? B1 : B0;
        int s = run_start128(m0, m1, pos);
        if (getbit128(u0, u1, pos)) {
            if (pos == s || !getbit128(u0, u1, pos - 1)) {
                int tgt = h ? A1 : A0;
                gunite(lab, myB - 1, tgt - 1);
            }
        } else {
            if (pos == s && pos > 0 && getbit128(u0, u1, pos - 1)) {
                int tgt = lab[baseA + (long)(pos - 1) * step];
                gunite(lab, myB - 1, tgt - 1);
            }
            bool isEnd = (pos == 127) || !getbit128(m0, m1, pos + 1);
            if (isEnd && pos < 127 && getbit128(u0, u1, pos + 1)) {
                int tgt = lab[baseA + (long)(pos + 1) * step];
                gunite(lab, myB - 1, tgt - 1);
            }
        }
    }

    // corner diagonal links (horizontal chunks only, edge lanes)
    if (!vertical && lane == 0) {
        int y = (seam + 1) << 6;
        int xbase = chunk << 7;
        if (xbase > 0 && (m0 & 1) && !(u0 & 1)) {          // NW corner
            int tgt = lab[(long)(y - 1) * W + xbase - 1];
            if (tgt) gunite(lab, B0 - 1, tgt - 1);
        }
        if (xbase + 128 < W && ((m1 >> 63) & 1) && !((u1 >> 63) & 1)) {  // NE
            int tgt = lab[(long)(y - 1) * W + xbase + 128];
            if (tgt) {
                int b127 = lab[(long)y * W + xbase + 127];
                gunite(lab, b127 - 1, tgt - 1);
            }
        }
    }
}

// READ-ONLY compress: the union-find tree is static in this kernel, so no
// halving writes (4M atomicMins aimed at a few thousand root cachelines
// would serialize). Plain loads: kernel-launch boundary invalidates stale
// L1; in-kernel writes only store FINAL root values, which are themselves
// valid ancestors for any concurrent reader.
__global__ __launch_bounds__(256)
void k_compress(int* __restrict__ lab) {
    int i = blockIdx.x * blockDim.x + threadIdx.x;
    if (i >= NPIX) return;
    int v = lab[i];
    if (v == 0) return;                  // bg
    int a = v - 1;
    int n = lab[a];
    while (n != a + 1) { a = n - 1; n = lab[a]; }
    if (a + 1 != v) lab[i] = a + 1;      // root+1 is the component min
}

extern "C" void kernel_launch(void* const* d_in, const int* in_sizes, int n_in,
                              void* d_out, int out_size, void* d_ws, size_t ws_size,
                              hipStream_t stream) {
    const float* prob = (const float*)d_in[0];
    int* lab = (int*)d_out;

    dim3 lgrid(W / TSX, H / TSY);        // 16 x 32 = 512 blocks (2/CU)
    dim3 lblock(64, 16);                 // 1024 threads, 16 waves
    k_local<<<lgrid, lblock, 0, stream>>>(prob, lab);

    // 736 wave-tasks * 64 lanes = 47104 threads = 184 blocks exactly
    k_seam<<<184, 256, 0, stream>>>(lab);

    k_compress<<<NPIX / 256, 256, 0, stream>>>(lab);
}